// Round 1
// baseline (2261.020 us; speedup 1.0000x reference)
//
#include <hip/hip_runtime.h>

#define NN 50000
#define EE 800000
#define HH 160
#define LMD 768
#define NBLK 196   // ceil(NN/256)

__device__ __forceinline__ float lrelu(float v){ return v >= 0.f ? v : 0.01f*v; }

// ---------------- small encoders: h_cat cols 0..63 ----------------
__global__ __launch_bounds__(256) void enc_small_k(
    const float* __restrict__ npx, const float* __restrict__ ncx,
    const float* __restrict__ Wnp, const float* __restrict__ bnp,
    const float* __restrict__ Wnc, const float* __restrict__ bnc,
    float* __restrict__ out)
{
  int gid = blockIdx.x*256 + threadIdx.x;
  int row = gid >> 6, c = gid & 63;
  if (row >= NN) return;
  float acc;
  if (c < 32) {
    acc = bnp[c];
    #pragma unroll
    for (int k = 0; k < 6; ++k) acc += npx[row*6+k]*Wnp[k*32+c];
  } else {
    int cc = c - 32;
    acc = bnc[cc];
    #pragma unroll
    for (int k = 0; k < 11; ++k) acc += ncx[row*11+k]*Wnc[k*32+cc];
  }
  out[(size_t)row*HH + c] = lrelu(acc);
}

// ---------------- generic f32 GEMM: out[M=NN, C] = act(X[*,K]@W[K,C]+b) ----
// 256 threads, 64-row tile, K chunked by 32. X staged transposed (b128
// broadcast reads), W staged contiguous (conflict-free b32 reads).
template<int C>
__global__ __launch_bounds__(256) void gemm_k(
    const float* __restrict__ X, int ldx,
    const float* __restrict__ W, const float* __restrict__ bias,
    float* __restrict__ out, int ldo, int K, int leaky)
{
  constexpr int JM = (C + 31) / 32;
  __shared__ float Xst[32*68];
  __shared__ float Ws[32*C];
  const int t = threadIdx.x;
  const int ct = t & 31, rt = t >> 5;
  const int r0 = blockIdx.x * 64;

  float acc[8][JM];
  #pragma unroll
  for (int i = 0; i < 8; ++i)
    #pragma unroll
    for (int j = 0; j < JM; ++j) acc[i][j] = 0.f;

  for (int k0 = 0; k0 < K; k0 += 32) {
    #pragma unroll
    for (int i = 0; i < 8; ++i) {
      int idx = t + i*256;
      int row = idx >> 5, kk = idx & 31;
      int gr = r0 + row;
      Xst[kk*68 + row] = (gr < NN) ? X[(size_t)gr*ldx + k0 + kk] : 0.f;
    }
    for (int idx = t; idx < 32*C; idx += 256)
      Ws[idx] = W[(size_t)k0*C + idx];
    __syncthreads();
    #pragma unroll
    for (int kk = 0; kk < 32; ++kk) {
      const float4 x0 = *(const float4*)&Xst[kk*68 + rt*8];
      const float4 x1 = *(const float4*)&Xst[kk*68 + rt*8 + 4];
      float wv[JM];
      #pragma unroll
      for (int j = 0; j < JM; ++j) {
        int c = ct + 32*j;
        wv[j] = (c < C) ? Ws[kk*C + c] : 0.f;
      }
      #pragma unroll
      for (int j = 0; j < JM; ++j) {
        acc[0][j] += x0.x*wv[j]; acc[1][j] += x0.y*wv[j];
        acc[2][j] += x0.z*wv[j]; acc[3][j] += x0.w*wv[j];
        acc[4][j] += x1.x*wv[j]; acc[5][j] += x1.y*wv[j];
        acc[6][j] += x1.z*wv[j]; acc[7][j] += x1.w*wv[j];
      }
    }
    __syncthreads();
  }

  #pragma unroll
  for (int i = 0; i < 8; ++i) {
    int gr = r0 + rt*8 + i;
    if (gr >= NN) continue;
    #pragma unroll
    for (int j = 0; j < JM; ++j) {
      int c = ct + 32*j;
      if (c < C) {
        float v = acc[i][j] + (bias ? bias[c] : 0.f);
        if (leaky) v = lrelu(v);
        out[(size_t)gr*ldo + c] = v;
      }
    }
  }
}

// ---------------- CSR build ----------------
__global__ __launch_bounds__(256) void hist_k(
    const int* __restrict__ dst, const int* __restrict__ et, int* __restrict__ cnt2)
{
  int e = blockIdx.x*256 + threadIdx.x;
  if (e < EE) atomicAdd(&cnt2[et[e]*NN + dst[e]], 1);
}

__global__ __launch_bounds__(256) void inv_k(
    const int* __restrict__ cnt2, float* __restrict__ inv2, int* __restrict__ cntall)
{
  int i = blockIdx.x*256 + threadIdx.x;
  if (i >= NN) return;
  int c0 = cnt2[i], c1 = cnt2[NN + i];
  inv2[i]      = 1.f / (float)max(c0, 1);
  inv2[NN + i] = 1.f / (float)max(c1, 1);
  cntall[i] = c0 + c1;
}

__global__ __launch_bounds__(256) void scan1_k(
    const int* __restrict__ cntall, int* __restrict__ off1, int* __restrict__ partials)
{
  __shared__ int sh[256];
  int t = threadIdx.x;
  int i = blockIdx.x*256 + t;
  sh[t] = (i < NN) ? cntall[i] : 0;
  __syncthreads();
  for (int s = 1; s < 256; s <<= 1) {
    int add = (t >= s) ? sh[t-s] : 0;
    __syncthreads();
    sh[t] += add;
    __syncthreads();
  }
  if (i < NN) off1[i] = sh[t];
  if (t == 255) partials[blockIdx.x] = sh[255];
}

__global__ __launch_bounds__(256) void scan2_k(int* __restrict__ partials)
{
  __shared__ int sh[256];
  int t = threadIdx.x;
  sh[t] = (t < NBLK) ? partials[t] : 0;
  __syncthreads();
  for (int s = 1; s < 256; s <<= 1) {
    int add = (t >= s) ? sh[t-s] : 0;
    __syncthreads();
    sh[t] += add;
    __syncthreads();
  }
  if (t < NBLK) partials[t] = (t == 0) ? 0 : sh[t-1];
}

__global__ __launch_bounds__(256) void scan3_k(
    int* __restrict__ off, int* __restrict__ cursor, const int* __restrict__ partials)
{
  int i = blockIdx.x*256 + threadIdx.x;
  if (i < NN) {
    int v = off[i+1] + partials[i >> 8];
    off[i+1] = v;
    if (i + 1 < NN) cursor[i+1] = v;
  }
  if (i == 0) { off[0] = 0; cursor[0] = 0; }
}

__global__ __launch_bounds__(256) void scatter_k(
    const int* __restrict__ src, const int* __restrict__ dst, const int* __restrict__ et,
    int* __restrict__ cursor, int* __restrict__ elist)
{
  int e = blockIdx.x*256 + threadIdx.x;
  if (e >= EE) return;
  int d = dst[e];
  int pos = atomicAdd(&cursor[d], 1);
  elist[pos] = (src[e] << 1) | et[e];
}

// ---------------- per-dst gather aggregate (no feature atomics) -------------
__global__ __launch_bounds__(256) void aggregate_k(
    const int* __restrict__ off, const int* __restrict__ elist,
    const float* __restrict__ inv2,
    const float* __restrict__ t0, const float* __restrict__ t1,
    float* __restrict__ acc)
{
  int gid = blockIdx.x*256 + threadIdx.x;
  int d = gid / 40, q = gid - d*40;
  if (d >= NN) return;
  int beg = off[d], end = off[d+1];
  float* ap = acc + (size_t)d*HH + q*4;
  float4 a = *(const float4*)ap;
  float i0 = inv2[d], i1 = inv2[NN + d];
  for (int p = beg; p < end; ++p) {
    int pk = elist[p];
    int s = pk >> 1;
    const float* tb = (pk & 1) ? t1 : t0;
    float sc = (pk & 1) ? i1 : i0;
    const float4 v = *(const float4*)(tb + (size_t)s*HH + q*4);
    a.x += v.x*sc; a.y += v.y*sc; a.z += v.z*sc; a.w += v.w*sc;
  }
  *(float4*)ap = a;
}

// ---------------- final 80->2 ----------------
__global__ __launch_bounds__(256) void final_k(
    const float* __restrict__ em, const float* __restrict__ W,
    const float* __restrict__ b, float* __restrict__ out)
{
  int row = blockIdx.x*256 + threadIdx.x;
  if (row >= NN) return;
  float a0 = b[0], a1 = b[1];
  const float* e = em + (size_t)row*80;
  #pragma unroll
  for (int k = 0; k < 80; ++k) { float v = e[k]; a0 += v*W[k*2]; a1 += v*W[k*2+1]; }
  out[row*2] = a0; out[row*2+1] = a1;
}

extern "C" void kernel_launch(void* const* d_in, const int* in_sizes, int n_in,
                              void* d_out, int out_size, void* d_ws, size_t ws_size,
                              hipStream_t stream)
{
  const float* pre_x   = (const float*)d_in[0];
  const int*   eidx    = (const int*)d_in[2];
  const int*   etype   = (const int*)d_in[3];
  const float* num_prop= (const float*)d_in[4];
  const float* num_cat = (const float*)d_in[5];
  const float* des     = (const float*)d_in[6];
  const float* tweet   = (const float*)d_in[7];
  const float* W_np=(const float*)d_in[8],  *b_np=(const float*)d_in[9];
  const float* W_nc=(const float*)d_in[10], *b_nc=(const float*)d_in[11];
  const float* W_des=(const float*)d_in[12],*b_des=(const float*)d_in[13];
  const float* W_text=(const float*)d_in[14],*b_text=(const float*)d_in[15];
  const float* W_tweet=(const float*)d_in[16],*b_tweet=(const float*)d_in[17];
  const float* W_in=(const float*)d_in[18], *b_in=(const float*)d_in[19];
  const float* W_rel1=(const float*)d_in[20], *W_root1=(const float*)d_in[21], *b_c1=(const float*)d_in[22];
  const float* W_rel2=(const float*)d_in[23], *W_root2=(const float*)d_in[24], *b_c2=(const float*)d_in[25];
  const float* W_o1=(const float*)d_in[26], *b_o1=(const float*)d_in[27];
  const float* W_o2=(const float*)d_in[28], *b_o2=(const float*)d_in[29];

  float* out = (float*)d_out;
  float* em  = out + (size_t)NN*2;     // output 1 region doubles as em buffer

  float* A  = (float*)d_ws;
  float* B  = A  + (size_t)NN*HH;
  float* T0 = B  + (size_t)NN*HH;
  float* T1 = T0 + (size_t)NN*HH;
  int*   cnt2    = (int*)(T1 + (size_t)NN*HH);
  float* inv2    = (float*)(cnt2 + 2*NN);
  int*   cntall  = (int*)(inv2 + 2*NN);
  int*   off     = cntall + NN;
  int*   partials= off + NN + 1;
  int*   cursor  = partials + 256;
  int*   elist   = cursor + NN;

  const int* src = eidx;
  const int* dst = eidx + EE;

  // ---- CSR build (reused by both conv layers) ----
  hipMemsetAsync(cnt2, 0, 2*NN*sizeof(int), stream);
  hist_k  <<<(EE+255)/256, 256, 0, stream>>>(dst, etype, cnt2);
  inv_k   <<<NBLK, 256, 0, stream>>>(cnt2, inv2, cntall);
  scan1_k <<<NBLK, 256, 0, stream>>>(cntall, off+1, partials);
  scan2_k <<<1,    256, 0, stream>>>(partials);
  scan3_k <<<NBLK, 256, 0, stream>>>(off, cursor, partials);
  scatter_k<<<(EE+255)/256, 256, 0, stream>>>(src, dst, etype, cursor, elist);

  // ---- encoders -> h_cat (A) ----
  enc_small_k<<<(NN*64+255)/256, 256, 0, stream>>>(num_prop, num_cat, W_np,b_np, W_nc,b_nc, A);
  const int GB = (NN + 63) / 64;
  gemm_k<32><<<GB,256,0,stream>>>(des,   LMD, W_des,   b_des,   A+64,  HH, LMD, 1);
  gemm_k<32><<<GB,256,0,stream>>>(tweet, LMD, W_text,  b_text,  A+96,  HH, LMD, 1);
  gemm_k<32><<<GB,256,0,stream>>>(pre_x, LMD, W_tweet, b_tweet, A+128, HH, LMD, 1);

  // ---- h0 = leaky(h_cat @ W_in + b) -> B ----
  gemm_k<160><<<GB,256,0,stream>>>(A, HH, W_in, b_in, B, HH, HH, 1);

  // ---- RGCN layer 1: acc in A ----
  gemm_k<160><<<GB,256,0,stream>>>(B, HH, W_root1, b_c1,   A,  HH, HH, 0);
  gemm_k<160><<<GB,256,0,stream>>>(B, HH, W_rel1,        nullptr, T0, HH, HH, 0);
  gemm_k<160><<<GB,256,0,stream>>>(B, HH, W_rel1 + HH*HH, nullptr, T1, HH, HH, 0);
  aggregate_k<<<(NN*40+255)/256, 256, 0, stream>>>(off, elist, inv2, T0, T1, A);

  // ---- RGCN layer 2: acc in B ----
  gemm_k<160><<<GB,256,0,stream>>>(A, HH, W_root2, b_c2,   B,  HH, HH, 0);
  gemm_k<160><<<GB,256,0,stream>>>(A, HH, W_rel2,        nullptr, T0, HH, HH, 0);
  gemm_k<160><<<GB,256,0,stream>>>(A, HH, W_rel2 + HH*HH, nullptr, T1, HH, HH, 0);
  aggregate_k<<<(NN*40+255)/256, 256, 0, stream>>>(off, elist, inv2, T0, T1, B);

  // ---- head ----
  gemm_k<80><<<GB,256,0,stream>>>(B, HH, W_o1, b_o1, em, 80, HH, 1);
  final_k<<<NBLK, 256, 0, stream>>>(em, W_o2, b_o2, out);
}

// Round 2
// 949.662 us; speedup vs baseline: 2.3809x; 2.3809x over previous
//
#include <hip/hip_runtime.h>

#define NN 50000
#define EE 800000
#define HH 160
#define LMD 768
#define NBLK 196   // ceil(NN/256)

typedef __attribute__((ext_vector_type(8))) short s8;
typedef __attribute__((ext_vector_type(4))) float f4;

__device__ __forceinline__ float lrelu(float v){ return v >= 0.f ? v : 0.01f*v; }

// f32 -> bf16 bits, round-to-nearest-even
__device__ __forceinline__ short f2b(float f){
  unsigned int u = __float_as_uint(f);
  unsigned int r = (u + 0x7fffu + ((u >> 16) & 1u)) >> 16;
  return (short)r;
}
__device__ __forceinline__ float b2f(short s){
  return __uint_as_float(((unsigned int)(unsigned short)s) << 16);
}

// ---------------- weight transpose+convert: W[K][C] f32 -> WT[C][K] bf16 ----
struct WD { const float* s; short* d; int K; int C; };
struct WDs { WD w[11]; };
__global__ __launch_bounds__(256) void wt_k(WDs ds)
{
  WD w = ds.w[blockIdx.y];
  int idx = blockIdx.x*256 + threadIdx.x;
  if (idx < w.K * w.C) {
    int k = idx / w.C, c = idx - k*w.C;
    w.d[(size_t)c*w.K + k] = f2b(w.s[idx]);
  }
}

// ---------------- small encoders: h_cat cols 0..63 (bf16 out) ----------------
__global__ __launch_bounds__(256) void enc_small_k(
    const float* __restrict__ npx, const float* __restrict__ ncx,
    const float* __restrict__ Wnp, const float* __restrict__ bnp,
    const float* __restrict__ Wnc, const float* __restrict__ bnc,
    short* __restrict__ out)
{
  int gid = blockIdx.x*256 + threadIdx.x;
  int row = gid >> 6, c = gid & 63;
  if (row >= NN) return;
  float acc;
  if (c < 32) {
    acc = bnp[c];
    #pragma unroll
    for (int k = 0; k < 6; ++k) acc += npx[row*6+k]*Wnp[k*32+c];
  } else {
    int cc = c - 32;
    acc = bnc[cc];
    #pragma unroll
    for (int k = 0; k < 11; ++k) acc += ncx[row*11+k]*Wnc[k*32+cc];
  }
  out[(size_t)row*HH + c] = f2b(lrelu(acc));
}

// ---------------- bf16 MFMA GEMM ----------------
// out[M=NN, C] = act(X[*,K] @ W[K,C] + b), W given transposed bf16 WT[C][K].
// 128-row block, 4 waves; wave w owns rows w*32..w*32+31 (two 16-row tiles),
// all C columns (NT=C/16 tiles). K chunked by 32 (one 16x16x32 MFMA per tile).
template<int C, bool XBF, bool OUTF32>
__global__ __launch_bounds__(256) void mgemm_k(
    const void* __restrict__ Xv, int ldx,
    const short* __restrict__ WT, const float* __restrict__ bias,
    void* __restrict__ outv, int ldo, int K, int leaky)
{
  constexpr int NT = C/16;
  __shared__ __attribute__((aligned(16))) short Xs[128*40];
  __shared__ __attribute__((aligned(16))) short Ws[C*40];
  const int t = threadIdx.x;
  const int r0 = blockIdx.x*128;
  const int w = t >> 6, L = t & 63;
  const int lm = L & 15, lq = L >> 4;

  f4 acc[2][NT];
  #pragma unroll
  for (int i = 0; i < 2; ++i)
    #pragma unroll
    for (int j = 0; j < NT; ++j) acc[i][j] = (f4){0.f,0.f,0.f,0.f};

  for (int k0 = 0; k0 < K; k0 += 32) {
    // stage X tile: 128 rows x 32 k (convert f32->bf16 if needed)
    #pragma unroll
    for (int i = t; i < 512; i += 256) {
      int row = i >> 2, kg = i & 3;
      int gr = r0 + row;
      s8 v;
      if (gr < NN) {
        if (XBF) {
          v = *(const s8*)((const short*)Xv + (size_t)gr*ldx + k0 + kg*8);
        } else {
          const float* xp = (const float*)Xv + (size_t)gr*ldx + k0 + kg*8;
          float4 a = *(const float4*)xp;
          float4 b = *(const float4*)(xp+4);
          v[0]=f2b(a.x); v[1]=f2b(a.y); v[2]=f2b(a.z); v[3]=f2b(a.w);
          v[4]=f2b(b.x); v[5]=f2b(b.y); v[6]=f2b(b.z); v[7]=f2b(b.w);
        }
      } else {
        v = (s8){0,0,0,0,0,0,0,0};
      }
      *(s8*)&Xs[row*40 + kg*8] = v;
    }
    // stage W tile: C cols x 32 k from WT[C][K] (already bf16, contiguous k)
    for (int i = t; i < C*4; i += 256) {
      int c = i >> 2, kg = i & 3;
      *(s8*)&Ws[c*40 + kg*8] = *(const s8*)(WT + (size_t)c*K + k0 + kg*8);
    }
    __syncthreads();
    s8 a0 = *(const s8*)&Xs[(w*32 + lm)*40 + lq*8];
    s8 a1 = *(const s8*)&Xs[(w*32 + 16 + lm)*40 + lq*8];
    #pragma unroll
    for (int j = 0; j < NT; ++j) {
      s8 bf = *(const s8*)&Ws[(j*16 + lm)*40 + lq*8];
      acc[0][j] = __builtin_amdgcn_mfma_f32_16x16x32_bf16(a0, bf, acc[0][j], 0, 0, 0);
      acc[1][j] = __builtin_amdgcn_mfma_f32_16x16x32_bf16(a1, bf, acc[1][j], 0, 0, 0);
    }
    __syncthreads();
  }

  // epilogue: C/D layout col=lane&15, row=(lane>>4)*4+r
  #pragma unroll
  for (int i = 0; i < 2; ++i) {
    #pragma unroll
    for (int j = 0; j < NT; ++j) {
      int col = j*16 + lm;
      float bv = bias ? bias[col] : 0.f;
      #pragma unroll
      for (int r = 0; r < 4; ++r) {
        int gr = r0 + w*32 + i*16 + lq*4 + r;
        if (gr < NN) {
          float v = acc[i][j][r] + bv;
          if (leaky) v = lrelu(v);
          if (OUTF32) ((float*)outv)[(size_t)gr*ldo + col] = v;
          else        ((short*)outv)[(size_t)gr*ldo + col] = f2b(v);
        }
      }
    }
  }
}

// ---------------- CSR build ----------------
__global__ __launch_bounds__(256) void hist_k(
    const int* __restrict__ dst, const int* __restrict__ et, int* __restrict__ cnt2)
{
  int e = blockIdx.x*256 + threadIdx.x;
  if (e < EE) atomicAdd(&cnt2[et[e]*NN + dst[e]], 1);
}

__global__ __launch_bounds__(256) void inv_k(
    const int* __restrict__ cnt2, float* __restrict__ inv2, int* __restrict__ cntall)
{
  int i = blockIdx.x*256 + threadIdx.x;
  if (i >= NN) return;
  int c0 = cnt2[i], c1 = cnt2[NN + i];
  inv2[i]      = 1.f / (float)max(c0, 1);
  inv2[NN + i] = 1.f / (float)max(c1, 1);
  cntall[i] = c0 + c1;
}

__global__ __launch_bounds__(256) void scan1_k(
    const int* __restrict__ cntall, int* __restrict__ off1, int* __restrict__ partials)
{
  __shared__ int sh[256];
  int t = threadIdx.x;
  int i = blockIdx.x*256 + t;
  sh[t] = (i < NN) ? cntall[i] : 0;
  __syncthreads();
  for (int s = 1; s < 256; s <<= 1) {
    int add = (t >= s) ? sh[t-s] : 0;
    __syncthreads();
    sh[t] += add;
    __syncthreads();
  }
  if (i < NN) off1[i] = sh[t];
  if (t == 255) partials[blockIdx.x] = sh[255];
}

__global__ __launch_bounds__(256) void scan2_k(int* __restrict__ partials)
{
  __shared__ int sh[256];
  int t = threadIdx.x;
  sh[t] = (t < NBLK) ? partials[t] : 0;
  __syncthreads();
  for (int s = 1; s < 256; s <<= 1) {
    int add = (t >= s) ? sh[t-s] : 0;
    __syncthreads();
    sh[t] += add;
    __syncthreads();
  }
  if (t < NBLK) partials[t] = (t == 0) ? 0 : sh[t-1];
}

__global__ __launch_bounds__(256) void scan3_k(
    int* __restrict__ off, int* __restrict__ cursor, const int* __restrict__ partials)
{
  int i = blockIdx.x*256 + threadIdx.x;
  if (i < NN) {
    int v = off[i+1] + partials[i >> 8];
    off[i+1] = v;
    if (i + 1 < NN) cursor[i+1] = v;
  }
  if (i == 0) { off[0] = 0; cursor[0] = 0; }
}

__global__ __launch_bounds__(256) void scatter_k(
    const int* __restrict__ src, const int* __restrict__ dst, const int* __restrict__ et,
    int* __restrict__ cursor, int* __restrict__ elist)
{
  int e = blockIdx.x*256 + threadIdx.x;
  if (e >= EE) return;
  int d = dst[e];
  int pos = atomicAdd(&cursor[d], 1);
  elist[pos] = (src[e] << 1) | et[e];
}

// ---------------- per-dst gather aggregate (bf16 msgs, f32 accumulate) ------
__global__ __launch_bounds__(256) void aggregate_k(
    const int* __restrict__ off, const int* __restrict__ elist,
    const float* __restrict__ inv2,
    const short* __restrict__ t0, const short* __restrict__ t1,
    short* __restrict__ acc)
{
  int gid = blockIdx.x*256 + threadIdx.x;
  int d = gid / 20, q = gid - d*20;
  if (d >= NN) return;
  int beg = off[d], end = off[d+1];
  float i0 = inv2[d], i1 = inv2[NN + d];
  short* ap = acc + (size_t)d*HH + q*8;
  s8 rv = *(const s8*)ap;
  float a[8];
  #pragma unroll
  for (int i = 0; i < 8; ++i) a[i] = b2f(rv[i]);
  for (int p = beg; p < end; ++p) {
    int pk = elist[p];
    int s = pk >> 1;
    const short* tb = (pk & 1) ? t1 : t0;
    float sc = (pk & 1) ? i1 : i0;
    s8 v = *(const s8*)(tb + (size_t)s*HH + q*8);
    #pragma unroll
    for (int i = 0; i < 8; ++i) a[i] += b2f(v[i]) * sc;
  }
  s8 o;
  #pragma unroll
  for (int i = 0; i < 8; ++i) o[i] = f2b(a[i]);
  *(s8*)ap = o;
}

// ---------------- final 80->2 (f32) ----------------
__global__ __launch_bounds__(256) void final_k(
    const float* __restrict__ em, const float* __restrict__ W,
    const float* __restrict__ b, float* __restrict__ out)
{
  int row = blockIdx.x*256 + threadIdx.x;
  if (row >= NN) return;
  float a0 = b[0], a1 = b[1];
  const float* e = em + (size_t)row*80;
  #pragma unroll
  for (int k = 0; k < 80; ++k) { float v = e[k]; a0 += v*W[k*2]; a1 += v*W[k*2+1]; }
  out[row*2] = a0; out[row*2+1] = a1;
}

extern "C" void kernel_launch(void* const* d_in, const int* in_sizes, int n_in,
                              void* d_out, int out_size, void* d_ws, size_t ws_size,
                              hipStream_t stream)
{
  const float* pre_x   = (const float*)d_in[0];
  const int*   eidx    = (const int*)d_in[2];
  const int*   etype   = (const int*)d_in[3];
  const float* num_prop= (const float*)d_in[4];
  const float* num_cat = (const float*)d_in[5];
  const float* des     = (const float*)d_in[6];
  const float* tweet   = (const float*)d_in[7];
  const float* W_np=(const float*)d_in[8],  *b_np=(const float*)d_in[9];
  const float* W_nc=(const float*)d_in[10], *b_nc=(const float*)d_in[11];
  const float* W_des=(const float*)d_in[12],*b_des=(const float*)d_in[13];
  const float* W_text=(const float*)d_in[14],*b_text=(const float*)d_in[15];
  const float* W_tweet=(const float*)d_in[16],*b_tweet=(const float*)d_in[17];
  const float* W_in=(const float*)d_in[18], *b_in=(const float*)d_in[19];
  const float* W_rel1=(const float*)d_in[20], *W_root1=(const float*)d_in[21], *b_c1=(const float*)d_in[22];
  const float* W_rel2=(const float*)d_in[23], *W_root2=(const float*)d_in[24], *b_c2=(const float*)d_in[25];
  const float* W_o1=(const float*)d_in[26], *b_o1=(const float*)d_in[27];
  const float* W_o2=(const float*)d_in[28], *b_o2=(const float*)d_in[29];

  float* out = (float*)d_out;
  float* em  = out + (size_t)NN*2;     // output 1 region (f32 em)

  // ---- ws layout (bf16 feature buffers + bf16 weights + CSR ints) ----
  short* A  = (short*)d_ws;            // N x 160 bf16
  short* Bb = A  + (size_t)NN*HH;
  short* T0 = Bb + (size_t)NN*HH;
  short* T1 = T0 + (size_t)NN*HH;
  short* WT = T1 + (size_t)NN*HH;      // 265728 bf16 total
  short* WT_des    = WT;               // [32][768]
  short* WT_text   = WT +  24576;
  short* WT_tweet  = WT +  49152;
  short* WT_in     = WT +  73728;      // [160][160]
  short* WT_root1  = WT +  99328;
  short* WT_rel1_0 = WT + 124928;
  short* WT_rel1_1 = WT + 150528;
  short* WT_root2  = WT + 176128;
  short* WT_rel2_0 = WT + 201728;
  short* WT_rel2_1 = WT + 227328;
  short* WT_o1     = WT + 252928;      // [80][160]

  int*   cnt2    = (int*)(WT + 265728);
  float* inv2    = (float*)(cnt2 + 2*NN);
  int*   cntall  = (int*)(inv2 + 2*NN);
  int*   off     = cntall + NN;
  int*   partials= off + NN + 1;
  int*   cursor  = partials + 256;
  int*   elist   = cursor + NN;

  const int* src = eidx;
  const int* dst = eidx + EE;

  // ---- weight conversion (must precede gemms; same stream = ordered) ----
  WDs ds;
  ds.w[0]  = (WD){W_des,          WT_des,    LMD, 32};
  ds.w[1]  = (WD){W_text,         WT_text,   LMD, 32};
  ds.w[2]  = (WD){W_tweet,        WT_tweet,  LMD, 32};
  ds.w[3]  = (WD){W_in,           WT_in,     HH, HH};
  ds.w[4]  = (WD){W_root1,        WT_root1,  HH, HH};
  ds.w[5]  = (WD){W_rel1,         WT_rel1_0, HH, HH};
  ds.w[6]  = (WD){W_rel1 + HH*HH, WT_rel1_1, HH, HH};
  ds.w[7]  = (WD){W_root2,        WT_root2,  HH, HH};
  ds.w[8]  = (WD){W_rel2,         WT_rel2_0, HH, HH};
  ds.w[9]  = (WD){W_rel2 + HH*HH, WT_rel2_1, HH, HH};
  ds.w[10] = (WD){W_o1,           WT_o1,     HH, 80};
  wt_k<<<dim3(100, 11), 256, 0, stream>>>(ds);

  // ---- CSR build ----
  hipMemsetAsync(cnt2, 0, 2*NN*sizeof(int), stream);
  hist_k  <<<(EE+255)/256, 256, 0, stream>>>(dst, etype, cnt2);
  inv_k   <<<NBLK, 256, 0, stream>>>(cnt2, inv2, cntall);
  scan1_k <<<NBLK, 256, 0, stream>>>(cntall, off+1, partials);
  scan2_k <<<1,    256, 0, stream>>>(partials);
  scan3_k <<<NBLK, 256, 0, stream>>>(off, cursor, partials);
  scatter_k<<<(EE+255)/256, 256, 0, stream>>>(src, dst, etype, cursor, elist);

  // ---- encoders -> h_cat (A, bf16) ----
  enc_small_k<<<(NN*64+255)/256, 256, 0, stream>>>(num_prop, num_cat, W_np,b_np, W_nc,b_nc, A);
  const int GB = (NN + 127) / 128;
  mgemm_k<32,false,false><<<GB,256,0,stream>>>(des,   LMD, WT_des,   b_des,   A+64,  HH, LMD, 1);
  mgemm_k<32,false,false><<<GB,256,0,stream>>>(tweet, LMD, WT_text,  b_text,  A+96,  HH, LMD, 1);
  mgemm_k<32,false,false><<<GB,256,0,stream>>>(pre_x, LMD, WT_tweet, b_tweet, A+128, HH, LMD, 1);

  // ---- h0 = leaky(h_cat @ W_in + b) -> Bb ----
  mgemm_k<160,true,false><<<GB,256,0,stream>>>(A, HH, WT_in, b_in, Bb, HH, HH, 1);

  // ---- RGCN layer 1: acc in A ----
  mgemm_k<160,true,false><<<GB,256,0,stream>>>(Bb, HH, WT_root1, b_c1, A, HH, HH, 0);
  mgemm_k<160,true,false><<<GB,256,0,stream>>>(Bb, HH, WT_rel1_0, nullptr, T0, HH, HH, 0);
  mgemm_k<160,true,false><<<GB,256,0,stream>>>(Bb, HH, WT_rel1_1, nullptr, T1, HH, HH, 0);
  aggregate_k<<<(NN*20+255)/256, 256, 0, stream>>>(off, elist, inv2, T0, T1, A);

  // ---- RGCN layer 2: acc in Bb ----
  mgemm_k<160,true,false><<<GB,256,0,stream>>>(A, HH, WT_root2, b_c2, Bb, HH, HH, 0);
  mgemm_k<160,true,false><<<GB,256,0,stream>>>(A, HH, WT_rel2_0, nullptr, T0, HH, HH, 0);
  mgemm_k<160,true,false><<<GB,256,0,stream>>>(A, HH, WT_rel2_1, nullptr, T1, HH, HH, 0);
  aggregate_k<<<(NN*20+255)/256, 256, 0, stream>>>(off, elist, inv2, T0, T1, Bb);

  // ---- head ----
  mgemm_k<80,true,true><<<GB,256,0,stream>>>(Bb, HH, WT_o1, b_o1, em, 80, HH, 1);
  final_k<<<NBLK, 256, 0, stream>>>(em, W_o2, b_o2, out);
}

// Round 3
// 908.901 us; speedup vs baseline: 2.4876x; 1.0448x over previous
//
#include <hip/hip_runtime.h>

#define NN 50000
#define EE 800000
#define HH 160
#define LMD 768
#define NBLK 196   // ceil(NN/256)

typedef __attribute__((ext_vector_type(8))) short s8;
typedef __attribute__((ext_vector_type(4))) float f4;

__device__ __forceinline__ float lrelu(float v){ return v >= 0.f ? v : 0.01f*v; }

__device__ __forceinline__ short f2b(float f){
  unsigned int u = __float_as_uint(f);
  unsigned int r = (u + 0x7fffu + ((u >> 16) & 1u)) >> 16;
  return (short)r;
}
__device__ __forceinline__ float b2f(short s){
  return __uint_as_float(((unsigned int)(unsigned short)s) << 16);
}

// ------- weight transpose+convert: W[K][C] f32 -> d[c*ldd + k] bf16 --------
struct WD { const float* s; short* d; int K; int C; int ldd; };
struct WDs { WD w[11]; };
__global__ __launch_bounds__(256) void wt_k(WDs ds)
{
  WD w = ds.w[blockIdx.y];
  int idx = blockIdx.x*256 + threadIdx.x;
  if (idx < w.K * w.C) {
    int k = idx / w.C, c = idx - k*w.C;
    w.d[(size_t)c*w.ldd + k] = f2b(w.s[idx]);
  }
}

// ------- small encoders: h_cat cols 0..63 (bf16) ---------------------------
__global__ __launch_bounds__(256) void enc_small_k(
    const float* __restrict__ npx, const float* __restrict__ ncx,
    const float* __restrict__ Wnp, const float* __restrict__ bnp,
    const float* __restrict__ Wnc, const float* __restrict__ bnc,
    short* __restrict__ out)
{
  int gid = blockIdx.x*256 + threadIdx.x;
  int row = gid >> 6, c = gid & 63;
  if (row >= NN) return;
  float acc;
  if (c < 32) {
    acc = bnp[c];
    #pragma unroll
    for (int k = 0; k < 6; ++k) acc += npx[row*6+k]*Wnp[k*32+c];
  } else {
    int cc = c - 32;
    acc = bnc[cc];
    #pragma unroll
    for (int k = 0; k < 11; ++k) acc += ncx[row*11+k]*Wnc[k*32+cc];
  }
  out[(size_t)row*HH + c] = f2b(lrelu(acc));
}

// ------- bf16 MFMA GEMM: out[NN,C] = act(X[*,K]@W[K,C]+b), WT[C][K] bf16 ---
template<int C, bool XBF>
__global__ __launch_bounds__(256) void mgemm_k(
    const void* __restrict__ Xv, int ldx,
    const short* __restrict__ WT, const float* __restrict__ bias,
    short* __restrict__ outb, int ldo, int K, int leaky)
{
  constexpr int NT = C/16;
  __shared__ __attribute__((aligned(16))) short Xs[128*40];
  __shared__ __attribute__((aligned(16))) short Ws[C*40];
  const int t = threadIdx.x;
  const int r0 = blockIdx.x*128;
  const int w = t >> 6, L = t & 63;
  const int lm = L & 15, lq = L >> 4;

  f4 acc[2][NT];
  #pragma unroll
  for (int i = 0; i < 2; ++i)
    #pragma unroll
    for (int j = 0; j < NT; ++j) acc[i][j] = (f4){0.f,0.f,0.f,0.f};

  for (int k0 = 0; k0 < K; k0 += 32) {
    for (int i = t; i < 512; i += 256) {
      int row = i >> 2, kg = i & 3;
      int gr = r0 + row;
      s8 v;
      if (gr < NN) {
        if (XBF) {
          v = *(const s8*)((const short*)Xv + (size_t)gr*ldx + k0 + kg*8);
        } else {
          const float* xp = (const float*)Xv + (size_t)gr*ldx + k0 + kg*8;
          float4 a = *(const float4*)xp;
          float4 b = *(const float4*)(xp+4);
          v[0]=f2b(a.x); v[1]=f2b(a.y); v[2]=f2b(a.z); v[3]=f2b(a.w);
          v[4]=f2b(b.x); v[5]=f2b(b.y); v[6]=f2b(b.z); v[7]=f2b(b.w);
        }
      } else {
        v = (s8){0,0,0,0,0,0,0,0};
      }
      *(s8*)&Xs[row*40 + kg*8] = v;
    }
    for (int i = t; i < C*4; i += 256) {
      int c = i >> 2, kg = i & 3;
      *(s8*)&Ws[c*40 + kg*8] = *(const s8*)(WT + (size_t)c*K + k0 + kg*8);
    }
    __syncthreads();
    s8 a0 = *(const s8*)&Xs[(w*32 + lm)*40 + lq*8];
    s8 a1 = *(const s8*)&Xs[(w*32 + 16 + lm)*40 + lq*8];
    #pragma unroll
    for (int j = 0; j < NT; ++j) {
      s8 bf = *(const s8*)&Ws[(j*16 + lm)*40 + lq*8];
      acc[0][j] = __builtin_amdgcn_mfma_f32_16x16x32_bf16(a0, bf, acc[0][j], 0, 0, 0);
      acc[1][j] = __builtin_amdgcn_mfma_f32_16x16x32_bf16(a1, bf, acc[1][j], 0, 0, 0);
    }
    __syncthreads();
  }

  #pragma unroll
  for (int i = 0; i < 2; ++i) {
    #pragma unroll
    for (int j = 0; j < NT; ++j) {
      int col = j*16 + lm;
      float bv = bias ? bias[col] : 0.f;
      #pragma unroll
      for (int r = 0; r < 4; ++r) {
        int gr = r0 + w*32 + i*16 + lq*4 + r;
        if (gr < NN) {
          float v = acc[i][j][r] + bv;
          if (leaky) v = lrelu(v);
          outb[(size_t)gr*ldo + col] = f2b(v);
        }
      }
    }
  }
}

// ------- head GEMM C=80 (K=160) + fused 80->2 final ------------------------
__global__ __launch_bounds__(256) void head_k(
    const short* __restrict__ X,
    const short* __restrict__ WT, const float* __restrict__ bias,
    const float* __restrict__ W2, const float* __restrict__ b2,
    float* __restrict__ em, float* __restrict__ out)
{
  constexpr int C = 80, NT = 5;
  __shared__ __attribute__((aligned(16))) short Xs[128*40];
  __shared__ __attribute__((aligned(16))) short Ws[C*40];
  __shared__ float emS[128][81];
  const int t = threadIdx.x;
  const int r0 = blockIdx.x*128;
  const int w = t >> 6, L = t & 63;
  const int lm = L & 15, lq = L >> 4;

  f4 acc[2][NT];
  #pragma unroll
  for (int i = 0; i < 2; ++i)
    #pragma unroll
    for (int j = 0; j < NT; ++j) acc[i][j] = (f4){0.f,0.f,0.f,0.f};

  for (int k0 = 0; k0 < HH; k0 += 32) {
    for (int i = t; i < 512; i += 256) {
      int row = i >> 2, kg = i & 3;
      int gr = r0 + row;
      s8 v = (s8){0,0,0,0,0,0,0,0};
      if (gr < NN) v = *(const s8*)(X + (size_t)gr*HH + k0 + kg*8);
      *(s8*)&Xs[row*40 + kg*8] = v;
    }
    for (int i = t; i < C*4; i += 256) {
      int c = i >> 2, kg = i & 3;
      *(s8*)&Ws[c*40 + kg*8] = *(const s8*)(WT + (size_t)c*HH + k0 + kg*8);
    }
    __syncthreads();
    s8 a0 = *(const s8*)&Xs[(w*32 + lm)*40 + lq*8];
    s8 a1 = *(const s8*)&Xs[(w*32 + 16 + lm)*40 + lq*8];
    #pragma unroll
    for (int j = 0; j < NT; ++j) {
      s8 bf = *(const s8*)&Ws[(j*16 + lm)*40 + lq*8];
      acc[0][j] = __builtin_amdgcn_mfma_f32_16x16x32_bf16(a0, bf, acc[0][j], 0, 0, 0);
      acc[1][j] = __builtin_amdgcn_mfma_f32_16x16x32_bf16(a1, bf, acc[1][j], 0, 0, 0);
    }
    __syncthreads();
  }

  #pragma unroll
  for (int i = 0; i < 2; ++i) {
    #pragma unroll
    for (int j = 0; j < NT; ++j) {
      int col = j*16 + lm;
      float bv = bias[col];
      #pragma unroll
      for (int r = 0; r < 4; ++r) {
        int lr = w*32 + i*16 + lq*4 + r;
        int gr = r0 + lr;
        if (gr < NN) {
          float v = lrelu(acc[i][j][r] + bv);
          em[(size_t)gr*80 + col] = v;
          emS[lr][col] = v;
        }
      }
    }
  }
  __syncthreads();
  if (t < 128) {
    int gr = r0 + t;
    if (gr < NN) {
      float a0 = b2[0], a1 = b2[1];
      #pragma unroll
      for (int k = 0; k < 80; ++k) {
        float v = emS[t][k];
        a0 += v*W2[k*2]; a1 += v*W2[k*2+1];
      }
      out[gr*2] = a0; out[gr*2+1] = a1;
    }
  }
}

// ------- CSR build ---------------------------------------------------------
__global__ __launch_bounds__(256) void hist_k(
    const int* __restrict__ dst, const int* __restrict__ et, int* __restrict__ cnt2)
{
  int e = blockIdx.x*256 + threadIdx.x;
  if (e < EE) atomicAdd(&cnt2[et[e]*NN + dst[e]], 1);
}

__global__ __launch_bounds__(256) void inv_k(
    const int* __restrict__ cnt2, float* __restrict__ inv2, int* __restrict__ cntall)
{
  int i = blockIdx.x*256 + threadIdx.x;
  if (i >= NN) return;
  int c0 = cnt2[i], c1 = cnt2[NN + i];
  inv2[i]      = 1.f / (float)max(c0, 1);
  inv2[NN + i] = 1.f / (float)max(c1, 1);
  cntall[i] = c0 + c1;
}

__global__ __launch_bounds__(256) void scan1_k(
    const int* __restrict__ cntall, int* __restrict__ off1, int* __restrict__ partials)
{
  __shared__ int sh[256];
  int t = threadIdx.x;
  int i = blockIdx.x*256 + t;
  sh[t] = (i < NN) ? cntall[i] : 0;
  __syncthreads();
  for (int s = 1; s < 256; s <<= 1) {
    int add = (t >= s) ? sh[t-s] : 0;
    __syncthreads();
    sh[t] += add;
    __syncthreads();
  }
  if (i < NN) off1[i] = sh[t];
  if (t == 255) partials[blockIdx.x] = sh[255];
}

__global__ __launch_bounds__(256) void scan2_k(int* __restrict__ partials)
{
  __shared__ int sh[256];
  int t = threadIdx.x;
  sh[t] = (t < NBLK) ? partials[t] : 0;
  __syncthreads();
  for (int s = 1; s < 256; s <<= 1) {
    int add = (t >= s) ? sh[t-s] : 0;
    __syncthreads();
    sh[t] += add;
    __syncthreads();
  }
  if (t < NBLK) partials[t] = (t == 0) ? 0 : sh[t-1];
}

__global__ __launch_bounds__(256) void scan3_k(
    int* __restrict__ off, int* __restrict__ cursor, const int* __restrict__ partials)
{
  int i = blockIdx.x*256 + threadIdx.x;
  if (i < NN) {
    int v = off[i+1] + partials[i >> 8];
    off[i+1] = v;
    if (i + 1 < NN) cursor[i+1] = v;
  }
  if (i == 0) { off[0] = 0; cursor[0] = 0; }
}

__global__ __launch_bounds__(256) void scatter_k(
    const int* __restrict__ src, const int* __restrict__ dst, const int* __restrict__ et,
    int* __restrict__ cursor, int* __restrict__ elist)
{
  int e = blockIdx.x*256 + threadIdx.x;
  if (e >= EE) return;
  int d = dst[e];
  int pos = atomicAdd(&cursor[d], 1);
  elist[pos] = (src[e] << 1) | et[e];
}

// ------- per-dst gather of RAW h, per-relation means (writes agg0|agg1) ----
// X layout: [NN][480] bf16; cols 0:160 = h (input), 160:320 = agg0, 320:480 = agg1.
__global__ __launch_bounds__(256) void aggregate_k(
    const int* __restrict__ off, const int* __restrict__ elist,
    const float* __restrict__ inv2, short* __restrict__ X)
{
  int gid = blockIdx.x*256 + threadIdx.x;
  int d = gid / 20, q = gid - d*20;
  if (d >= NN) return;
  int beg = off[d], end = off[d+1];
  float a0[8], a1[8];
  #pragma unroll
  for (int i = 0; i < 8; ++i) { a0[i] = 0.f; a1[i] = 0.f; }
  for (int p = beg; p < end; ++p) {
    int pk = elist[p];
    int s = pk >> 1;
    float m1 = (float)(pk & 1), m0 = 1.f - m1;
    s8 v = *(const s8*)(X + (size_t)s*480 + q*8);
    #pragma unroll
    for (int i = 0; i < 8; ++i) {
      float f = b2f(v[i]);
      a0[i] += f*m0; a1[i] += f*m1;
    }
  }
  float i0 = inv2[d], i1 = inv2[NN + d];
  s8 o0, o1;
  #pragma unroll
  for (int i = 0; i < 8; ++i) { o0[i] = f2b(a0[i]*i0); o1[i] = f2b(a1[i]*i1); }
  *(s8*)(X + (size_t)d*480 + 160 + q*8) = o0;
  *(s8*)(X + (size_t)d*480 + 320 + q*8) = o1;
}

extern "C" void kernel_launch(void* const* d_in, const int* in_sizes, int n_in,
                              void* d_out, int out_size, void* d_ws, size_t ws_size,
                              hipStream_t stream)
{
  const float* pre_x   = (const float*)d_in[0];
  const int*   eidx    = (const int*)d_in[2];
  const int*   etype   = (const int*)d_in[3];
  const float* num_prop= (const float*)d_in[4];
  const float* num_cat = (const float*)d_in[5];
  const float* des     = (const float*)d_in[6];
  const float* tweet   = (const float*)d_in[7];
  const float* W_np=(const float*)d_in[8],  *b_np=(const float*)d_in[9];
  const float* W_nc=(const float*)d_in[10], *b_nc=(const float*)d_in[11];
  const float* W_des=(const float*)d_in[12],*b_des=(const float*)d_in[13];
  const float* W_text=(const float*)d_in[14],*b_text=(const float*)d_in[15];
  const float* W_tweet=(const float*)d_in[16],*b_tweet=(const float*)d_in[17];
  const float* W_in=(const float*)d_in[18], *b_in=(const float*)d_in[19];
  const float* W_rel1=(const float*)d_in[20], *W_root1=(const float*)d_in[21], *b_c1=(const float*)d_in[22];
  const float* W_rel2=(const float*)d_in[23], *W_root2=(const float*)d_in[24], *b_c2=(const float*)d_in[25];
  const float* W_o1=(const float*)d_in[26], *b_o1=(const float*)d_in[27];
  const float* W_o2=(const float*)d_in[28], *b_o2=(const float*)d_in[29];

  float* out = (float*)d_out;
  float* em  = out + (size_t)NN*2;

  // ---- ws layout ----
  short* Acat = (short*)d_ws;               // [NN][160] h_cat, reused for h2
  short* X1   = Acat + (size_t)NN*HH;       // [NN][480] h0|agg0|agg1
  short* X2   = X1   + (size_t)NN*480;      // [NN][480] h1|agg0|agg1
  short* WT   = X2   + (size_t)NN*480;
  short* WT_des   = WT;                      // [32][768]
  short* WT_text  = WT +  24576;
  short* WT_tweet = WT +  49152;
  short* WT_in    = WT +  73728;             // [160][160]
  short* WT_cat1  = WT +  99328;             // [160][480]
  short* WT_cat2  = WT + 176128;             // [160][480]
  short* WT_o1    = WT + 252928;             // [80][160]

  int*   cnt2    = (int*)(WT + 265728);
  float* inv2    = (float*)(cnt2 + 2*NN);
  int*   cntall  = (int*)(inv2 + 2*NN);
  int*   off     = cntall + NN;
  int*   partials= off + NN + 1;
  int*   cursor  = partials + 256;
  int*   elist   = cursor + NN;

  const int* src = eidx;
  const int* dst = eidx + EE;

  // ---- weight conversion ----
  WDs ds;
  ds.w[0]  = (WD){W_des,          WT_des,         LMD, 32, LMD};
  ds.w[1]  = (WD){W_text,         WT_text,        LMD, 32, LMD};
  ds.w[2]  = (WD){W_tweet,        WT_tweet,       LMD, 32, LMD};
  ds.w[3]  = (WD){W_in,           WT_in,          HH, HH, HH};
  ds.w[4]  = (WD){W_root1,        WT_cat1,        HH, HH, 480};
  ds.w[5]  = (WD){W_rel1,         WT_cat1 + 160,  HH, HH, 480};
  ds.w[6]  = (WD){W_rel1 + HH*HH, WT_cat1 + 320,  HH, HH, 480};
  ds.w[7]  = (WD){W_root2,        WT_cat2,        HH, HH, 480};
  ds.w[8]  = (WD){W_rel2,         WT_cat2 + 160,  HH, HH, 480};
  ds.w[9]  = (WD){W_rel2 + HH*HH, WT_cat2 + 320,  HH, HH, 480};
  ds.w[10] = (WD){W_o1,           WT_o1,          HH, 80, HH};
  wt_k<<<dim3(100, 11), 256, 0, stream>>>(ds);

  // ---- CSR build ----
  hipMemsetAsync(cnt2, 0, 2*NN*sizeof(int), stream);
  hist_k  <<<(EE+255)/256, 256, 0, stream>>>(dst, etype, cnt2);
  inv_k   <<<NBLK, 256, 0, stream>>>(cnt2, inv2, cntall);
  scan1_k <<<NBLK, 256, 0, stream>>>(cntall, off+1, partials);
  scan2_k <<<1,    256, 0, stream>>>(partials);
  scan3_k <<<NBLK, 256, 0, stream>>>(off, cursor, partials);
  scatter_k<<<(EE+255)/256, 256, 0, stream>>>(src, dst, etype, cursor, elist);

  // ---- encoders -> Acat ----
  enc_small_k<<<(NN*64+255)/256, 256, 0, stream>>>(num_prop, num_cat, W_np,b_np, W_nc,b_nc, Acat);
  const int GB = (NN + 127) / 128;
  mgemm_k<32,false><<<GB,256,0,stream>>>(des,   LMD, WT_des,   b_des,   Acat+64,  HH, LMD, 1);
  mgemm_k<32,false><<<GB,256,0,stream>>>(tweet, LMD, WT_text,  b_text,  Acat+96,  HH, LMD, 1);
  mgemm_k<32,false><<<GB,256,0,stream>>>(pre_x, LMD, WT_tweet, b_tweet, Acat+128, HH, LMD, 1);

  // ---- h0 -> X1[:,0:160] ----
  mgemm_k<160,true><<<GB,256,0,stream>>>(Acat, HH, WT_in, b_in, X1, 480, HH, 1);

  // ---- layer 1: aggregate raw h0, then one K=480 GEMM -> X2[:,0:160] ----
  aggregate_k<<<(NN*20+255)/256, 256, 0, stream>>>(off, elist, inv2, X1);
  mgemm_k<160,true><<<GB,256,0,stream>>>(X1, 480, WT_cat1, b_c1, X2, 480, 480, 0);

  // ---- layer 2 -> h2 in Acat ----
  aggregate_k<<<(NN*20+255)/256, 256, 0, stream>>>(off, elist, inv2, X2);
  mgemm_k<160,true><<<GB,256,0,stream>>>(X2, 480, WT_cat2, b_c2, Acat, HH, 480, 0);

  // ---- head (fused em + out) ----
  head_k<<<GB,256,0,stream>>>(Acat, WT_o1, b_o1, W_o2, b_o2, em, out);
}

// Round 4
// 819.212 us; speedup vs baseline: 2.7600x; 1.1095x over previous
//
#include <hip/hip_runtime.h>

#define NN 50000
#define EE 800000
#define HH 160
#define LMD 768
#define NBLK 196   // ceil(NN/256)
#define GB64 782   // ceil(NN/64)

typedef __attribute__((ext_vector_type(8))) short s8;
typedef __attribute__((ext_vector_type(4))) float f4;

__device__ __forceinline__ float lrelu(float v){ return v >= 0.f ? v : 0.01f*v; }

__device__ __forceinline__ short f2b(float f){
  unsigned int u = __float_as_uint(f);
  unsigned int r = (u + 0x7fffu + ((u >> 16) & 1u)) >> 16;
  return (short)r;
}
__device__ __forceinline__ float b2f(short s){
  return __uint_as_float(((unsigned int)(unsigned short)s) << 16);
}

// ------- weight transpose+convert W[K][C] f32 -> d[c*ldd+k] bf16; y==11 zeroes cnt2
struct WD { const float* s; short* d; int K; int C; int ldd; };
struct WDs { WD w[11]; int* cnt2; };
__global__ __launch_bounds__(256) void wt_k(WDs ds)
{
  if (blockIdx.y == 11) {
    int idx = blockIdx.x*256 + threadIdx.x;
    #pragma unroll
    for (int j = 0; j < 4; ++j) {
      int i = idx + j*25600;
      if (i < 2*NN) ds.cnt2[i] = 0;
    }
    return;
  }
  WD w = ds.w[blockIdx.y];
  int idx = blockIdx.x*256 + threadIdx.x;
  if (idx < w.K * w.C) {
    int k = idx / w.C, c = idx - k*w.C;
    w.d[(size_t)c*w.ldd + k] = f2b(w.s[idx]);
  }
}

// ------- small encoders: h_cat cols 0..63 (bf16) ---------------------------
__global__ __launch_bounds__(256) void enc_small_k(
    const float* __restrict__ npx, const float* __restrict__ ncx,
    const float* __restrict__ Wnp, const float* __restrict__ bnp,
    const float* __restrict__ Wnc, const float* __restrict__ bnc,
    short* __restrict__ out)
{
  int gid = blockIdx.x*256 + threadIdx.x;
  int row = gid >> 6, c = gid & 63;
  if (row >= NN) return;
  float acc;
  if (c < 32) {
    acc = bnp[c];
    #pragma unroll
    for (int k = 0; k < 6; ++k) acc += npx[row*6+k]*Wnp[k*32+c];
  } else {
    int cc = c - 32;
    acc = bnc[cc];
    #pragma unroll
    for (int k = 0; k < 11; ++k) acc += ncx[row*11+k]*Wnc[k*32+cc];
  }
  out[(size_t)row*HH + c] = f2b(lrelu(acc));
}

// ------- pipelined bf16 MFMA GEMM body: 64-row tile, 4 waves, reg prefetch --
// out[NN,C] = act(X[*,K]@W[K,C]+b); WT is [C][K] bf16.
template<int C, bool XBF>
__device__ __forceinline__ void gemm_body(
    const void* __restrict__ Xv, int ldx,
    const short* __restrict__ WT, const float* __restrict__ bias,
    short* __restrict__ outb, int ldo, int K, int leaky, int r0)
{
  constexpr int NT = C/16;
  constexpr int NW = (C*4 + 255)/256;
  __shared__ __attribute__((aligned(16))) short Xs[64*40];
  __shared__ __attribute__((aligned(16))) short Ws[C*40];
  const int t = threadIdx.x;
  const int w = t >> 6, L = t & 63;
  const int lm = L & 15, lq = L >> 4;
  const int srow = t >> 2, skg = t & 3;
  const int gr = r0 + srow;

  f4 acc[NT];
  #pragma unroll
  for (int j = 0; j < NT; ++j) acc[j] = (f4){0.f,0.f,0.f,0.f};

  s8 xv = (s8){0,0,0,0,0,0,0,0};
  s8 wv[NW];

  // prologue: chunk 0 into regs
  if (gr < NN) {
    if (XBF) {
      xv = *(const s8*)((const short*)Xv + (size_t)gr*ldx + skg*8);
    } else {
      const float* xp = (const float*)Xv + (size_t)gr*ldx + skg*8;
      float4 a = *(const float4*)xp, b = *(const float4*)(xp+4);
      xv[0]=f2b(a.x); xv[1]=f2b(a.y); xv[2]=f2b(a.z); xv[3]=f2b(a.w);
      xv[4]=f2b(b.x); xv[5]=f2b(b.y); xv[6]=f2b(b.z); xv[7]=f2b(b.w);
    }
  }
  #pragma unroll
  for (int s = 0; s < NW; ++s) {
    int i = t + s*256;
    if (i < C*4) { int c = i>>2, kg = i&3; wv[s] = *(const s8*)(WT + (size_t)c*K + kg*8); }
  }

  for (int k0 = 0; k0 < K; k0 += 32) {
    if (k0) __syncthreads();                    // prior chunk's readers done
    *(s8*)&Xs[srow*40 + skg*8] = xv;
    #pragma unroll
    for (int s = 0; s < NW; ++s) {
      int i = t + s*256;
      if (i < C*4) { int c = i>>2, kg = i&3; *(s8*)&Ws[c*40 + kg*8] = wv[s]; }
    }
    __syncthreads();
    // prefetch next chunk while MFMAs run
    int kn = k0 + 32;
    if (kn < K) {
      if (gr < NN) {
        if (XBF) {
          xv = *(const s8*)((const short*)Xv + (size_t)gr*ldx + kn + skg*8);
        } else {
          const float* xp = (const float*)Xv + (size_t)gr*ldx + kn + skg*8;
          float4 a = *(const float4*)xp, b = *(const float4*)(xp+4);
          xv[0]=f2b(a.x); xv[1]=f2b(a.y); xv[2]=f2b(a.z); xv[3]=f2b(a.w);
          xv[4]=f2b(b.x); xv[5]=f2b(b.y); xv[6]=f2b(b.z); xv[7]=f2b(b.w);
        }
      }
      #pragma unroll
      for (int s = 0; s < NW; ++s) {
        int i = t + s*256;
        if (i < C*4) { int c = i>>2, kg = i&3; wv[s] = *(const s8*)(WT + (size_t)c*K + kn + kg*8); }
      }
    }
    s8 a = *(const s8*)&Xs[(w*16 + lm)*40 + lq*8];
    #pragma unroll
    for (int j = 0; j < NT; ++j) {
      s8 bf = *(const s8*)&Ws[(j*16 + lm)*40 + lq*8];
      acc[j] = __builtin_amdgcn_mfma_f32_16x16x32_bf16(a, bf, acc[j], 0, 0, 0);
    }
  }

  #pragma unroll
  for (int j = 0; j < NT; ++j) {
    int col = j*16 + lm;
    float bv = bias ? bias[col] : 0.f;
    #pragma unroll
    for (int r = 0; r < 4; ++r) {
      int go = r0 + w*16 + lq*4 + r;
      if (go < NN) {
        float v = acc[j][r] + bv;
        if (leaky) v = lrelu(v);
        outb[(size_t)go*ldo + col] = f2b(v);
      }
    }
  }
}

// three 768->32 encoders in one launch (blockIdx.y = which)
struct Enc3 { const float* X[3]; const short* WT[3]; const float* B[3]; short* out[3]; };
__global__ __launch_bounds__(256) void enc3_k(Enc3 e)
{
  int j = blockIdx.y;
  gemm_body<32,false>(e.X[j], LMD, e.WT[j], e.B[j], e.out[j], HH, LMD, 1, blockIdx.x*64);
}

__global__ __launch_bounds__(256) void dgemm_k(
    const short* __restrict__ X, int ldx,
    const short* __restrict__ WT, const float* __restrict__ bias,
    short* __restrict__ outb, int ldo, int K, int leaky)
{
  gemm_body<160,true>(X, ldx, WT, bias, outb, ldo, K, leaky, blockIdx.x*64);
}

// ------- head GEMM C=80 (K=160) + fused 80->2 final ------------------------
__global__ __launch_bounds__(256) void head_k(
    const short* __restrict__ X,
    const short* __restrict__ WT, const float* __restrict__ bias,
    const float* __restrict__ W2, const float* __restrict__ b2,
    float* __restrict__ em, float* __restrict__ out)
{
  constexpr int C = 80, NT = 5;
  __shared__ __attribute__((aligned(16))) short Xs[128*40];
  __shared__ __attribute__((aligned(16))) short Ws[C*40];
  __shared__ float emS[128][81];
  const int t = threadIdx.x;
  const int r0 = blockIdx.x*128;
  const int w = t >> 6, L = t & 63;
  const int lm = L & 15, lq = L >> 4;

  f4 acc[2][NT];
  #pragma unroll
  for (int i = 0; i < 2; ++i)
    #pragma unroll
    for (int j = 0; j < NT; ++j) acc[i][j] = (f4){0.f,0.f,0.f,0.f};

  for (int k0 = 0; k0 < HH; k0 += 32) {
    for (int i = t; i < 512; i += 256) {
      int row = i >> 2, kg = i & 3;
      int gr = r0 + row;
      s8 v = (s8){0,0,0,0,0,0,0,0};
      if (gr < NN) v = *(const s8*)(X + (size_t)gr*HH + k0 + kg*8);
      *(s8*)&Xs[row*40 + kg*8] = v;
    }
    for (int i = t; i < C*4; i += 256) {
      int c = i >> 2, kg = i & 3;
      *(s8*)&Ws[c*40 + kg*8] = *(const s8*)(WT + (size_t)c*HH + k0 + kg*8);
    }
    __syncthreads();
    s8 a0 = *(const s8*)&Xs[(w*32 + lm)*40 + lq*8];
    s8 a1 = *(const s8*)&Xs[(w*32 + 16 + lm)*40 + lq*8];
    #pragma unroll
    for (int j = 0; j < NT; ++j) {
      s8 bf = *(const s8*)&Ws[(j*16 + lm)*40 + lq*8];
      acc[0][j] = __builtin_amdgcn_mfma_f32_16x16x32_bf16(a0, bf, acc[0][j], 0, 0, 0);
      acc[1][j] = __builtin_amdgcn_mfma_f32_16x16x32_bf16(a1, bf, acc[1][j], 0, 0, 0);
    }
    __syncthreads();
  }

  #pragma unroll
  for (int i = 0; i < 2; ++i) {
    #pragma unroll
    for (int j = 0; j < NT; ++j) {
      int col = j*16 + lm;
      float bv = bias[col];
      #pragma unroll
      for (int r = 0; r < 4; ++r) {
        int lr = w*32 + i*16 + lq*4 + r;
        int gr = r0 + lr;
        if (gr < NN) {
          float v = lrelu(acc[i][j][r] + bv);
          em[(size_t)gr*80 + col] = v;
          emS[lr][col] = v;
        }
      }
    }
  }
  __syncthreads();
  if (t < 128) {
    int gr = r0 + t;
    if (gr < NN) {
      float a0 = b2[0], a1 = b2[1];
      #pragma unroll
      for (int k = 0; k < 80; ++k) {
        float v = emS[t][k];
        a0 += v*W2[k*2]; a1 += v*W2[k*2+1];
      }
      out[gr*2] = a0; out[gr*2+1] = a1;
    }
  }
}

// ------- CSR build ---------------------------------------------------------
__global__ __launch_bounds__(256) void hist_k(
    const int* __restrict__ dst, const int* __restrict__ et, int* __restrict__ cnt2)
{
  int e = blockIdx.x*256 + threadIdx.x;
  if (e < EE) atomicAdd(&cnt2[et[e]*NN + dst[e]], 1);
}

// fused: inverse-count + block-scan of total degree
__global__ __launch_bounds__(256) void scan1_k(
    const int* __restrict__ cnt2, float* __restrict__ inv2,
    int* __restrict__ off1, int* __restrict__ partials)
{
  __shared__ int sh[256];
  int t = threadIdx.x;
  int i = blockIdx.x*256 + t;
  int c0 = 0, c1 = 0;
  if (i < NN) {
    c0 = cnt2[i]; c1 = cnt2[NN + i];
    inv2[i]      = 1.f / (float)max(c0, 1);
    inv2[NN + i] = 1.f / (float)max(c1, 1);
  }
  sh[t] = c0 + c1;
  __syncthreads();
  for (int s = 1; s < 256; s <<= 1) {
    int add = (t >= s) ? sh[t-s] : 0;
    __syncthreads();
    sh[t] += add;
    __syncthreads();
  }
  if (i < NN) off1[i] = sh[t];
  if (t == 255) partials[blockIdx.x] = sh[255];
}

__global__ __launch_bounds__(256) void scan2_k(int* __restrict__ partials)
{
  __shared__ int sh[256];
  int t = threadIdx.x;
  sh[t] = (t < NBLK) ? partials[t] : 0;
  __syncthreads();
  for (int s = 1; s < 256; s <<= 1) {
    int add = (t >= s) ? sh[t-s] : 0;
    __syncthreads();
    sh[t] += add;
    __syncthreads();
  }
  if (t < NBLK) partials[t] = (t == 0) ? 0 : sh[t-1];
}

__global__ __launch_bounds__(256) void scan3_k(
    int* __restrict__ off, int* __restrict__ cursor, const int* __restrict__ partials)
{
  int i = blockIdx.x*256 + threadIdx.x;
  if (i < NN) {
    int v = off[i+1] + partials[i >> 8];
    off[i+1] = v;
    if (i + 1 < NN) cursor[i+1] = v;
  }
  if (i == 0) { off[0] = 0; cursor[0] = 0; }
}

__global__ __launch_bounds__(256) void scatter_k(
    const int* __restrict__ src, const int* __restrict__ dst, const int* __restrict__ et,
    int* __restrict__ cursor, int* __restrict__ elist)
{
  int e = blockIdx.x*256 + threadIdx.x;
  if (e >= EE) return;
  int d = dst[e];
  int pos = atomicAdd(&cursor[d], 1);
  elist[pos] = (src[e] << 1) | et[e];
}

// ------- per-dst gather of RAW h, per-relation means (2x edge unroll) ------
// X: [NN][480] bf16; cols 0:160 = h (input), 160:320 = agg0, 320:480 = agg1.
__global__ __launch_bounds__(256) void aggregate_k(
    const int* __restrict__ off, const int* __restrict__ elist,
    const float* __restrict__ inv2, short* __restrict__ X)
{
  int gid = blockIdx.x*256 + threadIdx.x;
  int d = gid / 20, q = gid - d*20;
  if (d >= NN) return;
  int beg = off[d], end = off[d+1];
  float a0[8], a1[8];
  #pragma unroll
  for (int i = 0; i < 8; ++i) { a0[i] = 0.f; a1[i] = 0.f; }
  int p = beg;
  for (; p + 2 <= end; p += 2) {
    int pk0 = elist[p], pk1 = elist[p+1];
    s8 v0 = *(const s8*)(X + (size_t)(pk0 >> 1)*480 + q*8);
    s8 v1 = *(const s8*)(X + (size_t)(pk1 >> 1)*480 + q*8);
    float m10 = (float)(pk0 & 1), m00 = 1.f - m10;
    float m11 = (float)(pk1 & 1), m01 = 1.f - m11;
    #pragma unroll
    for (int i = 0; i < 8; ++i) {
      float f0 = b2f(v0[i]), f1 = b2f(v1[i]);
      a0[i] += f0*m00 + f1*m01;
      a1[i] += f0*m10 + f1*m11;
    }
  }
  if (p < end) {
    int pk = elist[p];
    s8 v = *(const s8*)(X + (size_t)(pk >> 1)*480 + q*8);
    float m1 = (float)(pk & 1), m0 = 1.f - m1;
    #pragma unroll
    for (int i = 0; i < 8; ++i) {
      float f = b2f(v[i]);
      a0[i] += f*m0; a1[i] += f*m1;
    }
  }
  float i0 = inv2[d], i1 = inv2[NN + d];
  s8 o0, o1;
  #pragma unroll
  for (int i = 0; i < 8; ++i) { o0[i] = f2b(a0[i]*i0); o1[i] = f2b(a1[i]*i1); }
  *(s8*)(X + (size_t)d*480 + 160 + q*8) = o0;
  *(s8*)(X + (size_t)d*480 + 320 + q*8) = o1;
}

extern "C" void kernel_launch(void* const* d_in, const int* in_sizes, int n_in,
                              void* d_out, int out_size, void* d_ws, size_t ws_size,
                              hipStream_t stream)
{
  const float* pre_x   = (const float*)d_in[0];
  const int*   eidx    = (const int*)d_in[2];
  const int*   etype   = (const int*)d_in[3];
  const float* num_prop= (const float*)d_in[4];
  const float* num_cat = (const float*)d_in[5];
  const float* des     = (const float*)d_in[6];
  const float* tweet   = (const float*)d_in[7];
  const float* W_np=(const float*)d_in[8],  *b_np=(const float*)d_in[9];
  const float* W_nc=(const float*)d_in[10], *b_nc=(const float*)d_in[11];
  const float* W_des=(const float*)d_in[12],*b_des=(const float*)d_in[13];
  const float* W_text=(const float*)d_in[14],*b_text=(const float*)d_in[15];
  const float* W_tweet=(const float*)d_in[16],*b_tweet=(const float*)d_in[17];
  const float* W_in=(const float*)d_in[18], *b_in=(const float*)d_in[19];
  const float* W_rel1=(const float*)d_in[20], *W_root1=(const float*)d_in[21], *b_c1=(const float*)d_in[22];
  const float* W_rel2=(const float*)d_in[23], *W_root2=(const float*)d_in[24], *b_c2=(const float*)d_in[25];
  const float* W_o1=(const float*)d_in[26], *b_o1=(const float*)d_in[27];
  const float* W_o2=(const float*)d_in[28], *b_o2=(const float*)d_in[29];

  float* out = (float*)d_out;
  float* em  = out + (size_t)NN*2;

  // ---- ws layout ----
  short* Acat = (short*)d_ws;               // [NN][160] h_cat, reused for h2
  short* X1   = Acat + (size_t)NN*HH;       // [NN][480] h0|agg0|agg1
  short* X2   = X1   + (size_t)NN*480;      // [NN][480] h1|agg0|agg1
  short* WT   = X2   + (size_t)NN*480;
  short* WT_des   = WT;                      // [32][768]
  short* WT_text  = WT +  24576;
  short* WT_tweet = WT +  49152;
  short* WT_in    = WT +  73728;             // [160][160]
  short* WT_cat1  = WT +  99328;             // [160][480]
  short* WT_cat2  = WT + 176128;             // [160][480]
  short* WT_o1    = WT + 252928;             // [80][160]

  int*   cnt2    = (int*)(WT + 265728);
  float* inv2    = (float*)(cnt2 + 2*NN);
  int*   off     = (int*)(inv2 + 2*NN);
  int*   partials= off + NN + 1;
  int*   cursor  = partials + 256;
  int*   elist   = cursor + NN;

  const int* src = eidx;
  const int* dst = eidx + EE;

  // ---- weight conversion + cnt2 zero (y==11) ----
  WDs ds;
  ds.w[0]  = (WD){W_des,          WT_des,         LMD, 32, LMD};
  ds.w[1]  = (WD){W_text,         WT_text,        LMD, 32, LMD};
  ds.w[2]  = (WD){W_tweet,        WT_tweet,       LMD, 32, LMD};
  ds.w[3]  = (WD){W_in,           WT_in,          HH, HH, HH};
  ds.w[4]  = (WD){W_root1,        WT_cat1,        HH, HH, 480};
  ds.w[5]  = (WD){W_rel1,         WT_cat1 + 160,  HH, HH, 480};
  ds.w[6]  = (WD){W_rel1 + HH*HH, WT_cat1 + 320,  HH, HH, 480};
  ds.w[7]  = (WD){W_root2,        WT_cat2,        HH, HH, 480};
  ds.w[8]  = (WD){W_rel2,         WT_cat2 + 160,  HH, HH, 480};
  ds.w[9]  = (WD){W_rel2 + HH*HH, WT_cat2 + 320,  HH, HH, 480};
  ds.w[10] = (WD){W_o1,           WT_o1,          HH, 80, HH};
  ds.cnt2  = cnt2;
  wt_k<<<dim3(100, 12), 256, 0, stream>>>(ds);

  // ---- CSR build ----
  hist_k  <<<(EE+255)/256, 256, 0, stream>>>(dst, etype, cnt2);
  scan1_k <<<NBLK, 256, 0, stream>>>(cnt2, inv2, off+1, partials);
  scan2_k <<<1,    256, 0, stream>>>(partials);
  scan3_k <<<NBLK, 256, 0, stream>>>(off, cursor, partials);
  scatter_k<<<(EE+255)/256, 256, 0, stream>>>(src, dst, etype, cursor, elist);

  // ---- encoders -> Acat ----
  enc_small_k<<<(NN*64+255)/256, 256, 0, stream>>>(num_prop, num_cat, W_np,b_np, W_nc,b_nc, Acat);
  Enc3 e3;
  e3.X[0]=des;     e3.WT[0]=WT_des;   e3.B[0]=b_des;   e3.out[0]=Acat+64;
  e3.X[1]=tweet;   e3.WT[1]=WT_text;  e3.B[1]=b_text;  e3.out[1]=Acat+96;
  e3.X[2]=pre_x;   e3.WT[2]=WT_tweet; e3.B[2]=b_tweet; e3.out[2]=Acat+128;
  enc3_k<<<dim3(GB64, 3), 256, 0, stream>>>(e3);

  // ---- h0 -> X1[:,0:160] ----
  dgemm_k<<<GB64,256,0,stream>>>(Acat, HH, WT_in, b_in, X1, 480, HH, 1);

  // ---- layer 1: aggregate raw h0, then one K=480 GEMM -> X2[:,0:160] ----
  aggregate_k<<<(NN*20+255)/256, 256, 0, stream>>>(off, elist, inv2, X1);
  dgemm_k<<<GB64,256,0,stream>>>(X1, 480, WT_cat1, b_c1, X2, 480, 480, 0);

  // ---- layer 2 -> h2 in Acat ----
  aggregate_k<<<(NN*20+255)/256, 256, 0, stream>>>(off, elist, inv2, X2);
  dgemm_k<<<GB64,256,0,stream>>>(X2, 480, WT_cat2, b_c2, Acat, HH, 480, 0);

  // ---- head (fused em + out) ----
  head_k<<<(NN+127)/128,256,0,stream>>>(Acat, WT_o1, b_o1, W_o2, b_o2, em, out);
}